// Round 1
// baseline (896.721 us; speedup 1.0000x reference)
//
#include <hip/hip_runtime.h>

typedef float vfloat4 __attribute__((ext_vector_type(4)));

#define NBINS 4096
#define BPT (NBINS / 256)        // bins per thread in block-scan

#define FUSED_BLOCKS   4096
#define COMPACT_BLOCKS 2048

// workspace layout (u32 word offsets). Every word is written before read; no
// dependence on the 0xAA poison value.
#define OFF_COUNTER 0u           // [1]      candidate count
#define OFF_BINS    256u         // [4096]   summed histogram
#define OFF_SLICES  8192u        // [512*4096] per-block histogram slices
// candidate buffer follows the slices (capacity n0 words: safe even if every
// element of x[0] lands in one bin)

// ---------------------------------------------------------------------------
// Block-level rank-select over 4096 bins with 256 threads.
// On return res[0] = bin containing rank `krem` (1-indexed), res[1] = rank
// remaining inside that bin. Requires all bins visible to the block (caller
// syncs before call if bins live in LDS). Safe to call repeatedly.
__device__ __forceinline__ void select_bin(const unsigned* __restrict__ bins,
                                           unsigned krem,
                                           unsigned* csum, unsigned* res) {
  const int t = threadIdx.x;
  unsigned local[BPT];
  unsigned s = 0;
#pragma unroll
  for (int j = 0; j < BPT; ++j) { local[j] = bins[t * BPT + j]; s += local[j]; }
  csum[t] = s;
  __syncthreads();
  // Hillis-Steele inclusive scan over the 256 chunk sums
  for (int off = 1; off < 256; off <<= 1) {
    unsigned add = (t >= off) ? csum[t - off] : 0u;
    __syncthreads();
    csum[t] += add;
    __syncthreads();
  }
  unsigned incl = csum[t];
  unsigned excl = incl - s;
  if (krem > excl && krem <= incl) {   // exactly one thread
    unsigned run = excl;
#pragma unroll
    for (int j = 0; j < BPT; ++j) {
      if (krem <= run + local[j]) {
        res[0] = (unsigned)(t * BPT + j);
        res[1] = krem - run;
        break;
      }
      run += local[j];
    }
  }
  __syncthreads();
}

// ---------------------------------------------------------------------------
// SiLU over all of x (contiguous chunk per block, float4). Blocks covering
// batch 0 additionally histogram abs-bit patterns (bits [30:19]) into LDS and
// dump the raw 4096-bin slice to global (plain stores, no atomics).
__global__ __launch_bounds__(256) void fused_silu_hist(
    const vfloat4* __restrict__ x, vfloat4* __restrict__ out,
    int nvec, int nvec0, int vpb, unsigned* __restrict__ slices) {
  __shared__ unsigned lbins[NBINS];
  const int b = blockIdx.x;
  const int start = b * vpb;
  const int end = min(start + vpb, nvec);
  const bool do_hist = (start < nvec0);

  if (do_hist) {
    for (int j = threadIdx.x; j < NBINS; j += 256) lbins[j] = 0u;
    __syncthreads();
    for (int i = start + (int)threadIdx.x; i < end; i += 256) {
      vfloat4 v = x[i];
      if (i < nvec0) {
        unsigned a;
        a = __float_as_uint(v.x) & 0x7fffffffu; atomicAdd(&lbins[a >> 19], 1u);
        a = __float_as_uint(v.y) & 0x7fffffffu; atomicAdd(&lbins[a >> 19], 1u);
        a = __float_as_uint(v.z) & 0x7fffffffu; atomicAdd(&lbins[a >> 19], 1u);
        a = __float_as_uint(v.w) & 0x7fffffffu; atomicAdd(&lbins[a >> 19], 1u);
      }
      vfloat4 r;
      r.x = v.x / (1.0f + __expf(-v.x));
      r.y = v.y / (1.0f + __expf(-v.y));
      r.z = v.z / (1.0f + __expf(-v.z));
      r.w = v.w / (1.0f + __expf(-v.w));
      __builtin_nontemporal_store(r, &out[i]);
    }
    __syncthreads();
    unsigned* slice = slices + (size_t)b * NBINS;
    for (int j = threadIdx.x; j < NBINS; j += 256) slice[j] = lbins[j];
  } else {
    for (int i = start + (int)threadIdx.x; i < end; i += 256) {
      vfloat4 v = x[i];
      vfloat4 r;
      r.x = v.x / (1.0f + __expf(-v.x));
      r.y = v.y / (1.0f + __expf(-v.y));
      r.z = v.z / (1.0f + __expf(-v.z));
      r.w = v.w / (1.0f + __expf(-v.w));
      __builtin_nontemporal_store(r, &out[i]);
    }
  }
}

// ---------------------------------------------------------------------------
// Sum the per-block histogram slices into one 4096-bin histogram; zero the
// candidate counter for the compaction pass.
__global__ __launch_bounds__(256) void reduce_hist(
    const unsigned* __restrict__ slices, unsigned* __restrict__ bins,
    unsigned* __restrict__ counter, int hist_blocks) {
  const int j = blockIdx.x * 256 + threadIdx.x;   // 16 blocks -> 4096 bins
  unsigned s = 0;
  for (int b = 0; b < hist_blocks; ++b) s += slices[(size_t)b * NBINS + j];
  bins[j] = s;
  if (j == 0) *counter = 0u;
}

// ---------------------------------------------------------------------------
// Each block recomputes the pass-1 prefix from the summed bins (deterministic,
// identical in every block), then streams its chunk of x[0], compacting the
// abs-bit patterns that match the 12-bit prefix into the candidate buffer.
// Wave-aggregated atomics: one atomicAdd per matching ballot.
__global__ __launch_bounds__(256) void compact_kernel(
    const uint4* __restrict__ x, int nvec0, int vpb,
    const unsigned* __restrict__ bins, unsigned* __restrict__ counter,
    unsigned* __restrict__ cand, unsigned krem) {
  __shared__ unsigned csum[256];
  __shared__ unsigned res[2];
  select_bin(bins, krem, csum, res);
  const unsigned prefix12 = res[0];

  const int start = blockIdx.x * vpb;
  const int end = min(start + vpb, nvec0);
  const int lane = (int)(threadIdx.x & 63u);
  for (int i = start + (int)threadIdx.x; i < end; i += 256) {
    uint4 v = x[i];
    unsigned aa[4] = { v.x & 0x7fffffffu, v.y & 0x7fffffffu,
                       v.z & 0x7fffffffu, v.w & 0x7fffffffu };
#pragma unroll
    for (int c = 0; c < 4; ++c) {
      const unsigned abs_ = aa[c];
      const bool m = ((abs_ >> 19) == prefix12);
      const unsigned long long mk = __ballot(m);
      if (mk) {
        const int leader = __ffsll((long long)mk) - 1;
        unsigned base = 0;
        if (lane == leader) base = atomicAdd(counter, (unsigned)__popcll(mk));
        base = __shfl(base, leader);
        if (m) {
          const unsigned pos =
              (unsigned)__popcll(mk & ((1ull << (unsigned)lane) - 1ull));
          cand[base + pos] = abs_;
        }
      }
    }
  }
}

// ---------------------------------------------------------------------------
// Single block: finish the remaining 19 bits over the (small) candidate set.
// Pass A: bits [18:7] (4096 bins). Pass B: bits [6:0] (128 bins, zero-padded
// to 4096 so select_bin is reusable). Writes outliner + scale.
__global__ __launch_bounds__(256) void final_select_kernel(
    const unsigned* __restrict__ bins, const unsigned* __restrict__ counter,
    const unsigned* __restrict__ cand, unsigned krem,
    float* __restrict__ out_scalars) {
  __shared__ unsigned lbins[NBINS];
  __shared__ unsigned csum[256];
  __shared__ unsigned res[2];
  const int t = threadIdx.x;

  select_bin(bins, krem, csum, res);
  const unsigned prefix12 = res[0];
  const unsigned krem2 = res[1];
  __syncthreads();
  const unsigned nc = *counter;

  // pass A: bits [18:7]
  for (int j = t; j < NBINS; j += 256) lbins[j] = 0u;
  __syncthreads();
  for (unsigned i = (unsigned)t; i < nc; i += 256)
    atomicAdd(&lbins[(cand[i] >> 7) & 0xfffu], 1u);
  __syncthreads();
  select_bin(lbins, krem2, csum, res);
  const unsigned b2 = res[0];
  const unsigned krem3 = res[1];
  __syncthreads();

  // pass B: bits [6:0] among candidates matching bits [30:7]
  for (int j = t; j < NBINS; j += 256) lbins[j] = 0u;
  __syncthreads();
  const unsigned pref24 = (prefix12 << 12) | b2;   // bits [30:7]
  for (unsigned i = (unsigned)t; i < nc; i += 256) {
    const unsigned a = cand[i];
    if ((a >> 7) == pref24) atomicAdd(&lbins[a & 0x7fu], 1u);
  }
  __syncthreads();
  select_bin(lbins, krem3, csum, res);
  const unsigned b3 = res[0];

  if (t == 0) {
    const unsigned pattern = (pref24 << 7) | b3;
    const float v = __uint_as_float(pattern);
    out_scalars[0] = v;            // outliner (kth smallest |x[0]|)
    out_scalars[1] = v / 127.0f;   // scale = max|x_sub0|/127 == outliner/127
  }
}

// ---------------------------------------------------------------------------
extern "C" void kernel_launch(void* const* d_in, const int* in_sizes, int n_in,
                              void* d_out, int out_size, void* d_ws,
                              size_t ws_size, hipStream_t stream) {
  const float* x = (const float*)d_in[0];
  float* out = (float*)d_out;
  const int n = in_sizes[0];      // 8*2048*4096 = 67108864
  const int n0 = n / 8;           // one batch element
  // k = int(n0 * (1 - 0.01)), python int() truncation semantics
  const unsigned k = (unsigned)((double)n0 * 0.99);

  const int nvec  = n / 4;
  const int nvec0 = n0 / 4;

  unsigned* ws32    = (unsigned*)d_ws;
  unsigned* counter = ws32 + OFF_COUNTER;
  unsigned* bins    = ws32 + OFF_BINS;
  unsigned* slices  = ws32 + OFF_SLICES;

  const int vpb_f = (nvec + FUSED_BLOCKS - 1) / FUSED_BLOCKS;       // 4096
  const int hist_blocks = (nvec0 + vpb_f - 1) / vpb_f;              // 512
  unsigned* cand = slices + (size_t)hist_blocks * NBINS;
  const int vpb_c = (nvec0 + COMPACT_BLOCKS - 1) / COMPACT_BLOCKS;  // 1024

  fused_silu_hist<<<FUSED_BLOCKS, 256, 0, stream>>>(
      (const vfloat4*)x, (vfloat4*)out, nvec, nvec0, vpb_f, slices);
  reduce_hist<<<NBINS / 256, 256, 0, stream>>>(slices, bins, counter,
                                               hist_blocks);
  compact_kernel<<<COMPACT_BLOCKS, 256, 0, stream>>>(
      (const uint4*)x, nvec0, vpb_c, bins, counter, cand, k);
  final_select_kernel<<<1, 256, 0, stream>>>(bins, counter, cand, k, out + n);
}

// Round 3
// 501.207 us; speedup vs baseline: 1.7891x; 1.7891x over previous
//
#include <hip/hip_runtime.h>

// Round 3 = round 2 resubmitted verbatim: the bench failed on container
// acquisition (infra flake), not kernel correctness. Audit found no hangs,
// no LDS/workspace overflow, no conditional barriers.

typedef float vfloat4 __attribute__((ext_vector_type(4)));

#define NBINS 4096
#define BPT (NBINS / 256)        // bins per thread in block-scan

#define FUSED_BLOCKS   4096
#define COMPACT_BLOCKS 2048
#define REGION_CAP     4096      // == vpb_c * 4 elements; overflow impossible

// workspace layout (u32 word offsets). Every word is written before read; no
// dependence on the 0xAA poison value.
#define OFF_BINS    0u                       // [4096]   summed histogram
#define OFF_CNTS    4096u                    // [2048]   per-block candidate counts
#define OFF_SLICES  8192u                    // [512*4096] per-block histogram slices
// candidate regions follow: COMPACT_BLOCKS * REGION_CAP words (32 MiB)

// ---------------------------------------------------------------------------
// Block-level rank-select over 4096 bins with 256 threads.
// On return res[0] = bin containing rank `krem` (1-indexed), res[1] = rank
// remaining inside that bin. Trailing barrier makes res visible to all.
__device__ __forceinline__ void select_bin(const unsigned* __restrict__ bins,
                                           unsigned krem,
                                           unsigned* csum, unsigned* res) {
  const int t = threadIdx.x;
  unsigned local[BPT];
  unsigned s = 0;
#pragma unroll
  for (int j = 0; j < BPT; ++j) { local[j] = bins[t * BPT + j]; s += local[j]; }
  csum[t] = s;
  __syncthreads();
  // Hillis-Steele inclusive scan over the 256 chunk sums
  for (int off = 1; off < 256; off <<= 1) {
    unsigned add = (t >= off) ? csum[t - off] : 0u;
    __syncthreads();
    csum[t] += add;
    __syncthreads();
  }
  unsigned incl = csum[t];
  unsigned excl = incl - s;
  if (krem > excl && krem <= incl) {   // exactly one thread
    unsigned run = excl;
#pragma unroll
    for (int j = 0; j < BPT; ++j) {
      if (krem <= run + local[j]) {
        res[0] = (unsigned)(t * BPT + j);
        res[1] = krem - run;
        break;
      }
      run += local[j];
    }
  }
  __syncthreads();
}

// ---------------------------------------------------------------------------
// SiLU over all of x (contiguous chunk per block, float4). Blocks covering
// batch 0 additionally histogram abs-bit patterns (bits [30:19]) into LDS and
// dump the raw 4096-bin slice to global (plain stores, no atomics).
// Pure-silu blocks use non-temporal loads so batch 1..7 traffic does not
// evict x[0] from L3 (compact_kernel re-reads x[0] next).
__global__ __launch_bounds__(256) void fused_silu_hist(
    const vfloat4* __restrict__ x, vfloat4* __restrict__ out,
    int nvec, int nvec0, int vpb, unsigned* __restrict__ slices) {
  __shared__ unsigned lbins[NBINS];
  const int b = blockIdx.x;
  const int start = b * vpb;
  const int end = min(start + vpb, nvec);
  const bool do_hist = (start < nvec0);

  if (do_hist) {
    for (int j = threadIdx.x; j < NBINS; j += 256) lbins[j] = 0u;
    __syncthreads();
    for (int i = start + (int)threadIdx.x; i < end; i += 256) {
      vfloat4 v = x[i];
      if (i < nvec0) {
        unsigned a;
        a = __float_as_uint(v.x) & 0x7fffffffu; atomicAdd(&lbins[a >> 19], 1u);
        a = __float_as_uint(v.y) & 0x7fffffffu; atomicAdd(&lbins[a >> 19], 1u);
        a = __float_as_uint(v.z) & 0x7fffffffu; atomicAdd(&lbins[a >> 19], 1u);
        a = __float_as_uint(v.w) & 0x7fffffffu; atomicAdd(&lbins[a >> 19], 1u);
      }
      vfloat4 r;
      r.x = v.x / (1.0f + __expf(-v.x));
      r.y = v.y / (1.0f + __expf(-v.y));
      r.z = v.z / (1.0f + __expf(-v.z));
      r.w = v.w / (1.0f + __expf(-v.w));
      __builtin_nontemporal_store(r, &out[i]);
    }
    __syncthreads();
    unsigned* slice = slices + (size_t)b * NBINS;
    for (int j = threadIdx.x; j < NBINS; j += 256) slice[j] = lbins[j];
  } else {
    for (int i = start + (int)threadIdx.x; i < end; i += 256) {
      vfloat4 v = __builtin_nontemporal_load(&x[i]);
      vfloat4 r;
      r.x = v.x / (1.0f + __expf(-v.x));
      r.y = v.y / (1.0f + __expf(-v.y));
      r.z = v.z / (1.0f + __expf(-v.z));
      r.w = v.w / (1.0f + __expf(-v.w));
      __builtin_nontemporal_store(r, &out[i]);
    }
  }
}

// ---------------------------------------------------------------------------
// Sum the 512 per-block histogram slices into one 4096-bin histogram.
// 256 blocks x 256 threads: block handles 16 bins; 16 slice-subgroups per bin
// summed in parallel, then a small LDS tree reduction.
__global__ __launch_bounds__(256) void reduce_hist(
    const unsigned* __restrict__ slices, unsigned* __restrict__ bins,
    int nslices) {
  __shared__ unsigned part[16][17];   // [bin_local][slice_group], padded
  const int t = threadIdx.x;
  const int bl = t & 15;              // bin within this block's group of 16
  const int sg = t >> 4;              // slice subgroup 0..15
  const int bin = blockIdx.x * 16 + bl;
  unsigned s = 0;
  for (int b = sg; b < nslices; b += 16)
    s += slices[(size_t)b * NBINS + bin];
  part[bl][sg] = s;
  __syncthreads();
  for (int off = 8; off > 0; off >>= 1) {
    if (sg < off) part[bl][sg] += part[bl][sg + off];
    __syncthreads();
  }
  if (sg == 0) bins[bin] = part[bl][0];
}

// ---------------------------------------------------------------------------
// Each block recomputes the pass-1 prefix from the summed bins (deterministic,
// identical in every block), then streams its chunk of x[0], buffering the
// abs-bit patterns that match the 12-bit prefix in LDS (LDS atomic counter),
// and finally dumps them to its PRIVATE region with plain stores.
// ZERO global atomics.
__global__ __launch_bounds__(256) void compact_kernel(
    const uint4* __restrict__ x, int nvec0, int vpb,
    const unsigned* __restrict__ bins,
    unsigned* __restrict__ cnts, unsigned* __restrict__ cand,
    unsigned krem) {
  __shared__ unsigned csum[256];
  __shared__ unsigned res[2];
  __shared__ unsigned lcount;
  __shared__ unsigned lbuf[REGION_CAP];
  select_bin(bins, krem, csum, res);
  if (threadIdx.x == 0) lcount = 0u;
  __syncthreads();
  const unsigned prefix12 = res[0];

  const int start = blockIdx.x * vpb;
  const int end = min(start + vpb, nvec0);
  for (int i = start + (int)threadIdx.x; i < end; i += 256) {
    uint4 v = x[i];
    unsigned aa[4] = { v.x & 0x7fffffffu, v.y & 0x7fffffffu,
                       v.z & 0x7fffffffu, v.w & 0x7fffffffu };
#pragma unroll
    for (int c = 0; c < 4; ++c) {
      const unsigned abs_ = aa[c];
      if ((abs_ >> 19) == prefix12) {
        unsigned p = atomicAdd(&lcount, 1u);   // LDS atomic: cheap, in-CU
        lbuf[p] = abs_;
      }
    }
  }
  __syncthreads();
  const unsigned c = lcount;
  unsigned* region = cand + (size_t)blockIdx.x * REGION_CAP;
  for (unsigned i = threadIdx.x; i < c; i += 256) region[i] = lbuf[i];
  if (threadIdx.x == 0) cnts[blockIdx.x] = c;
}

// ---------------------------------------------------------------------------
// Single block: finish the remaining 19 bits over the candidate regions.
// Pass A: bits [18:7] (4096 bins). Pass B: bits [6:0] among candidates
// matching bits [30:7]. Writes outliner + scale.
__global__ __launch_bounds__(256) void final_select_kernel(
    const unsigned* __restrict__ bins, const unsigned* __restrict__ cnts,
    const unsigned* __restrict__ cand, int nregions, unsigned krem,
    float* __restrict__ out_scalars) {
  __shared__ unsigned lbins[NBINS];
  __shared__ unsigned csum[256];
  __shared__ unsigned res[2];
  const int t = threadIdx.x;

  select_bin(bins, krem, csum, res);
  const unsigned prefix12 = res[0];
  const unsigned krem2 = res[1];

  // pass A: bits [18:7]
  for (int j = t; j < NBINS; j += 256) lbins[j] = 0u;
  __syncthreads();
  for (int b = t; b < nregions; b += 256) {
    const unsigned c = cnts[b];
    const unsigned* reg = cand + (size_t)b * REGION_CAP;
    for (unsigned i = 0; i < c; ++i)
      atomicAdd(&lbins[(reg[i] >> 7) & 0xfffu], 1u);
  }
  __syncthreads();
  select_bin(lbins, krem2, csum, res);
  const unsigned b2 = res[0];
  const unsigned krem3 = res[1];

  // pass B: bits [6:0] among candidates matching bits [30:7]
  __syncthreads();
  for (int j = t; j < NBINS; j += 256) lbins[j] = 0u;
  __syncthreads();
  const unsigned pref24 = (prefix12 << 12) | b2;   // bits [30:7]
  for (int b = t; b < nregions; b += 256) {
    const unsigned c = cnts[b];
    const unsigned* reg = cand + (size_t)b * REGION_CAP;
    for (unsigned i = 0; i < c; ++i) {
      const unsigned a = reg[i];
      if ((a >> 7) == pref24) atomicAdd(&lbins[a & 0x7fu], 1u);
    }
  }
  __syncthreads();
  select_bin(lbins, krem3, csum, res);
  const unsigned b3 = res[0];

  if (t == 0) {
    const unsigned pattern = (pref24 << 7) | b3;
    const float v = __uint_as_float(pattern);
    out_scalars[0] = v;            // outliner (kth smallest |x[0]|)
    out_scalars[1] = v / 127.0f;   // scale = max|x_sub0|/127 == outliner/127
  }
}

// ---------------------------------------------------------------------------
extern "C" void kernel_launch(void* const* d_in, const int* in_sizes, int n_in,
                              void* d_out, int out_size, void* d_ws,
                              size_t ws_size, hipStream_t stream) {
  const float* x = (const float*)d_in[0];
  float* out = (float*)d_out;
  const int n = in_sizes[0];      // 8*2048*4096 = 67108864
  const int n0 = n / 8;           // one batch element
  // k = int(n0 * (1 - 0.01)), python int() truncation semantics
  const unsigned k = (unsigned)((double)n0 * 0.99);

  const int nvec  = n / 4;
  const int nvec0 = n0 / 4;

  unsigned* ws32   = (unsigned*)d_ws;
  unsigned* bins   = ws32 + OFF_BINS;
  unsigned* cnts   = ws32 + OFF_CNTS;
  unsigned* slices = ws32 + OFF_SLICES;

  const int vpb_f = (nvec + FUSED_BLOCKS - 1) / FUSED_BLOCKS;       // 4096
  const int hist_blocks = (nvec0 + vpb_f - 1) / vpb_f;              // 512
  unsigned* cand = slices + (size_t)hist_blocks * NBINS;
  const int vpb_c = (nvec0 + COMPACT_BLOCKS - 1) / COMPACT_BLOCKS;  // 1024

  fused_silu_hist<<<FUSED_BLOCKS, 256, 0, stream>>>(
      (const vfloat4*)x, (vfloat4*)out, nvec, nvec0, vpb_f, slices);
  reduce_hist<<<NBINS / 16, 256, 0, stream>>>(slices, bins, hist_blocks);
  compact_kernel<<<COMPACT_BLOCKS, 256, 0, stream>>>(
      (const uint4*)x, nvec0, vpb_c, bins, cnts, cand, k);
  final_select_kernel<<<1, 256, 0, stream>>>(bins, cnts, cand, COMPACT_BLOCKS,
                                             k, out + n);
}